// Round 1
// baseline (1225.755 us; speedup 1.0000x reference)
//
#include <hip/hip_runtime.h>

// Fused Swin-style window attention for MI355X (gfx950).
// One block (256 thr / 4 waves) per 8x8 window. FP16 MFMA (16x16x32),
// fp32 accumulate. Weights pre-converted to fp16 in d_ws by prep kernel.

typedef _Float16 half8 __attribute__((ext_vector_type(8)));
typedef float f32x4 __attribute__((ext_vector_type(4)));

#define XN_STR 264   // [tok][c] stride in halfs (pad 8 -> 2-way-only LDS aliasing)
#define QK_STR 40    // [tok][dh]
#define VT_STR 72    // [dh][tok]
#define P_STR  72    // [tok][tok]
#define XN_OFF 0
#define Q_OFF  (64 * XN_STR)
#define K_OFF  (Q_OFF + 64 * QK_STR)
#define VT_OFF (K_OFF + 64 * QK_STR)
#define P_OFF  (VT_OFF + 32 * VT_STR)
#define SM_TOT (P_OFF + 64 * P_STR)   // 28928 halfs = 57856 B

__global__ void __launch_bounds__(256)
prep_weights_f16(const float* __restrict__ w_in, const float* __restrict__ w_out,
                 _Float16* __restrict__ wh) {
    int i = blockIdx.x * 256 + threadIdx.x;
    if (i < 196608)      wh[i] = (_Float16)w_in[i];
    else if (i < 262144) wh[i] = (_Float16)w_out[i - 196608];
}

__global__ void __launch_bounds__(256, 2)
win_attn_fused(const float* __restrict__ x, const float* __restrict__ gamma,
               const float* __restrict__ beta, const float* __restrict__ b_in,
               const float* __restrict__ b_out,
               const _Float16* __restrict__ w_in_h,
               const _Float16* __restrict__ w_out_h,
               float* __restrict__ out)
{
    __shared__ __align__(16) _Float16 sm[SM_TOT];
    __shared__ float s_gb[512];

    const int tid = threadIdx.x;
    const int wid = blockIdx.x;
    const int b   = wid >> 8;
    const int whi = (wid >> 4) & 15;
    const int wwi = wid & 15;
    const int h0 = whi * 8, w0 = wwi * 8;

    s_gb[tid]       = gamma[tid];
    s_gb[256 + tid] = beta[tid];

    // ---- phase 0: gather window -> LDS [tok][c] (fp16) ----
    const float* xb = x + (((size_t)b * 256) * 128 + h0) * 128 + w0;
#pragma unroll
    for (int it = 0; it < 16; ++it) {
        int idx = tid + 256 * it;
        int q  = idx & 1;
        int th = (idx >> 1) & 7;
        int c  = idx >> 4;
        float4 v = *(const float4*)(xb + ((size_t)c * 128 + th) * 128 + q * 4);
        int t0 = th * 8 + q * 4;
        _Float16* dst = &sm[XN_OFF + c];
        dst[(t0 + 0) * XN_STR] = (_Float16)v.x;
        dst[(t0 + 1) * XN_STR] = (_Float16)v.y;
        dst[(t0 + 2) * XN_STR] = (_Float16)v.z;
        dst[(t0 + 3) * XN_STR] = (_Float16)v.w;
    }
    __syncthreads();

    // ---- LayerNorm: stats via 4-lane butterfly, normalize in place ----
    {
        int tok = tid >> 2, cq = tid & 3;
        int base = XN_OFF + tok * XN_STR + cq * 64;
        float sum = 0.f, ss = 0.f;
#pragma unroll
        for (int k2 = 0; k2 < 8; ++k2) {
            half8 hv = *(const half8*)&sm[base + k2 * 8];
#pragma unroll
            for (int j = 0; j < 8; ++j) { float f = (float)hv[j]; sum += f; ss += f * f; }
        }
        sum += __shfl_xor(sum, 1); ss += __shfl_xor(ss, 1);
        sum += __shfl_xor(sum, 2); ss += __shfl_xor(ss, 2);
        float mu   = sum * (1.f / 256.f);
        float var  = ss * (1.f / 256.f) - mu * mu;
        float rstd = rsqrtf(var + 1e-5f);
#pragma unroll
        for (int k2 = 0; k2 < 8; ++k2) {
            half8 hv = *(const half8*)&sm[base + k2 * 8];
            half8 o;
#pragma unroll
            for (int j = 0; j < 8; ++j) {
                int c = cq * 64 + k2 * 8 + j;
                float f = ((float)hv[j] - mu) * rstd;
                o[j] = (_Float16)(f * s_gb[c] + s_gb[256 + c]);
            }
            *(half8*)&sm[base + k2 * 8] = o;
        }
    }
    __syncthreads();

    const int wv   = tid >> 6;
    const int lane = tid & 63;
    const int quad = lane >> 4;
    const int l16  = lane & 15;
    const int tokb = 16 * wv + quad * 4;
    const f32x4 zero4 = {0.f, 0.f, 0.f, 0.f};

    f32x4 oacc[8][2];

    // ---- phase 1: per-head QKV -> attention ----
#pragma unroll
    for (int h = 0; h < 8; ++h) {
        int obase[6];
        obase[0] = h * 32;        obase[1] = h * 32 + 16;
        obase[2] = 256 + h * 32;  obase[3] = 256 + h * 32 + 16;
        obase[4] = 512 + h * 32;  obase[5] = 512 + h * 32 + 16;

        f32x4 acc[6];
#pragma unroll
        for (int ct = 0; ct < 6; ++ct) acc[ct] = zero4;

        const _Float16* arow = &sm[XN_OFF + (16 * wv + l16) * XN_STR + quad * 8];
        const _Float16* wrow[6];
#pragma unroll
        for (int ct = 0; ct < 6; ++ct)
            wrow[ct] = w_in_h + (size_t)(obase[ct] + l16) * 256 + quad * 8;

#pragma unroll
        for (int kb = 0; kb < 256; kb += 32) {
            half8 af = *(const half8*)(arow + kb);
#pragma unroll
            for (int ct = 0; ct < 6; ++ct) {
                half8 bf = *(const half8*)(wrow[ct] + kb);
                acc[ct] = __builtin_amdgcn_mfma_f32_16x16x32_f16(af, bf, acc[ct], 0, 0, 0);
            }
        }
#pragma unroll
        for (int ct = 0; ct < 6; ++ct) {
            float bi = b_in[obase[ct] + l16];
            acc[ct][0] += bi; acc[ct][1] += bi; acc[ct][2] += bi; acc[ct][3] += bi;
        }

        __syncthreads();   // all waves done reading previous head's Q/K/VT
#pragma unroll
        for (int r = 0; r < 4; ++r) {
            sm[Q_OFF  + (tokb + r) * QK_STR + l16]        = (_Float16)acc[0][r];
            sm[Q_OFF  + (tokb + r) * QK_STR + 16 + l16]   = (_Float16)acc[1][r];
            sm[K_OFF  + (tokb + r) * QK_STR + l16]        = (_Float16)acc[2][r];
            sm[K_OFF  + (tokb + r) * QK_STR + 16 + l16]   = (_Float16)acc[3][r];
            sm[VT_OFF + l16 * VT_STR        + tokb + r]   = (_Float16)acc[4][r];
            sm[VT_OFF + (16 + l16) * VT_STR + tokb + r]   = (_Float16)acc[5][r];
        }
        __syncthreads();   // Q/K/VT visible to all waves

        // scores: rows [16*wv,16*wv+16), all 64 cols; K=32 -> 1 MFMA per col-tile
        half8 aq = *(const half8*)&sm[Q_OFF + (16 * wv + l16) * QK_STR + quad * 8];
        f32x4 s[4];
#pragma unroll
        for (int ct = 0; ct < 4; ++ct) {
            half8 bk = *(const half8*)&sm[K_OFF + (ct * 16 + l16) * QK_STR + quad * 8];
            s[ct] = __builtin_amdgcn_mfma_f32_16x16x32_f16(aq, bk, zero4, 0, 0, 0);
            s[ct] *= 0.17677669529663687f;   // 1/sqrt(32)
        }
        // softmax per row (row = quad*4 + r; cols live in the 16-lane quad-group)
#pragma unroll
        for (int r = 0; r < 4; ++r) {
            float m = fmaxf(fmaxf(s[0][r], s[1][r]), fmaxf(s[2][r], s[3][r]));
            m = fmaxf(m, __shfl_xor(m, 1));
            m = fmaxf(m, __shfl_xor(m, 2));
            m = fmaxf(m, __shfl_xor(m, 4));
            m = fmaxf(m, __shfl_xor(m, 8));
            float sum = 0.f;
#pragma unroll
            for (int ct = 0; ct < 4; ++ct) {
                float e = exp2f((s[ct][r] - m) * 1.4426950408889634f);
                s[ct][r] = e;
                sum += e;
            }
            sum += __shfl_xor(sum, 1);
            sum += __shfl_xor(sum, 2);
            sum += __shfl_xor(sum, 4);
            sum += __shfl_xor(sum, 8);
            float rs = 1.f / sum;
#pragma unroll
            for (int ct = 0; ct < 4; ++ct)
                sm[P_OFF + (tokb + r) * P_STR + ct * 16 + l16] = (_Float16)(s[ct][r] * rs);
        }

        // P @ V  (M=16 strip, N=32, K=64) — P rows are wave-private
#pragma unroll
        for (int ct = 0; ct < 2; ++ct) {
            f32x4 oa = zero4;
#pragma unroll
            for (int kb = 0; kb < 64; kb += 32) {
                half8 ap = *(const half8*)&sm[P_OFF + (16 * wv + l16) * P_STR + kb + quad * 8];
                half8 bv = *(const half8*)&sm[VT_OFF + (ct * 16 + l16) * VT_STR + kb + quad * 8];
                oa = __builtin_amdgcn_mfma_f32_16x16x32_f16(ap, bv, oa, 0, 0, 0);
            }
            oacc[h][ct] = oa;
        }
    }

    __syncthreads();
    // ---- phase 2: attention output -> LDS obuf[tok][c] (reuse XN region) ----
#pragma unroll
    for (int h = 0; h < 8; ++h)
#pragma unroll
        for (int ct = 0; ct < 2; ++ct)
#pragma unroll
            for (int r = 0; r < 4; ++r)
                sm[XN_OFF + (tokb + r) * XN_STR + h * 32 + ct * 16 + l16] =
                    (_Float16)oacc[h][ct][r];
    __syncthreads();

    // ---- phase 3: y^T = w_out * obuf^T  (M=c rows, N=tok) ----
    f32x4 pacc[4][4];
#pragma unroll
    for (int mt = 0; mt < 4; ++mt)
#pragma unroll
        for (int nt = 0; nt < 4; ++nt) pacc[mt][nt] = zero4;

    const _Float16* wor = w_out_h + (size_t)(64 * wv + l16) * 256 + quad * 8;
#pragma unroll
    for (int kb = 0; kb < 256; kb += 32) {
        half8 aw[4], bo[4];
#pragma unroll
        for (int mt = 0; mt < 4; ++mt) aw[mt] = *(const half8*)(wor + mt * 16 * 256 + kb);
#pragma unroll
        for (int nt = 0; nt < 4; ++nt)
            bo[nt] = *(const half8*)&sm[XN_OFF + (nt * 16 + l16) * XN_STR + kb + quad * 8];
#pragma unroll
        for (int mt = 0; mt < 4; ++mt)
#pragma unroll
            for (int nt = 0; nt < 4; ++nt)
                pacc[mt][nt] = __builtin_amdgcn_mfma_f32_16x16x32_f16(aw[mt], bo[nt], pacc[mt][nt], 0, 0, 0);
    }

    // ---- epilogue: bias + scatter to (B,C,H,W) fp32 ----
    float* ob = out + (((size_t)b * 256) * 128 + h0) * 128 + w0;
#pragma unroll
    for (int mt = 0; mt < 4; ++mt) {
#pragma unroll
        for (int r = 0; r < 4; ++r) {
            int c = 64 * wv + mt * 16 + quad * 4 + r;
            float bi = b_out[c];
#pragma unroll
            for (int nt = 0; nt < 4; ++nt) {
                int tok = nt * 16 + l16;   // 16 consecutive tokens across lanes -> 32B segments
                ob[((size_t)c * 128 + (tok >> 3)) * 128 + (tok & 7)] = pacc[mt][nt][r] + bi;
            }
        }
    }
}

extern "C" void kernel_launch(void* const* d_in, const int* in_sizes, int n_in,
                              void* d_out, int out_size, void* d_ws, size_t ws_size,
                              hipStream_t stream) {
    const float* x        = (const float*)d_in[0];
    const float* ln_gamma = (const float*)d_in[1];
    const float* ln_beta  = (const float*)d_in[2];
    const float* w_in     = (const float*)d_in[3];
    const float* b_in     = (const float*)d_in[4];
    const float* w_out    = (const float*)d_in[5];
    const float* b_out    = (const float*)d_in[6];
    float* y = (float*)d_out;

    _Float16* w_in_h  = (_Float16*)d_ws;            // 196608 halfs
    _Float16* w_out_h = w_in_h + 196608;            // 65536 halfs

    prep_weights_f16<<<1024, 256, 0, stream>>>(w_in, w_out, w_in_h);
    win_attn_fused<<<4096, 256, 0, stream>>>(x, ln_gamma, ln_beta, b_in, b_out,
                                             w_in_h, w_out_h, y);
}